// Round 1
// baseline (9498.897 us; speedup 1.0000x reference)
//
#include <hip/hip_runtime.h>
#include <hip/hip_bf16.h>

#define B 64
#define L 128
#define E 512
#define H 512
#define V 32000
#define T 64

// ---------- helpers ----------
__device__ __forceinline__ unsigned long long pack_key(float v, int n) {
    unsigned u = __float_as_uint(v);
    u = (u & 0x80000000u) ? ~u : (u | 0x80000000u);   // order-preserving float->uint
    return ((unsigned long long)u << 32) | (unsigned)(~n); // tie -> smaller n wins (numpy argmax)
}

// ---------- kernel 1: h0 = z @ W_proj.T + b_proj; zero argmax slots ----------
__global__ __launch_bounds__(256) void init_kernel(
    const float* __restrict__ z, const float* __restrict__ W_proj,
    const float* __restrict__ b_proj, float* __restrict__ hbuf,
    unsigned long long* __restrict__ slots) {
    int idx = blockIdx.x * 256 + threadIdx.x;       // 128 blocks * 256 = 64*512
    int b = idx >> 9;
    int i = idx & 511;
    const float* zrow = z + b * L;                  // uniform within block
    const float* wrow = W_proj + (size_t)i * L;
    float acc = b_proj[i];
#pragma unroll
    for (int k = 0; k < L; k += 4) {
        float4 zv = *(const float4*)(zrow + k);
        float4 wv = *(const float4*)(wrow + k);
        acc = fmaf(zv.x, wv.x, acc);
        acc = fmaf(zv.y, wv.y, acc);
        acc = fmaf(zv.z, wv.z, acc);
        acc = fmaf(zv.w, wv.w, acc);
    }
    hbuf[b * H + i] = acc;                          // h[0] = h0
    if (idx < 128) slots[idx] = 0ull;               // both slot buffers
}

// ---------- kernel 2: GRU cell ----------
// grid 128, block (64,4). One wave per hidden index i; lanes = batch b.
// x source: slots-fed emb gather (or h0 on step 0).
__global__ __launch_bounds__(256) void gru_kernel(
    const float* __restrict__ hsrc, const float* __restrict__ x0,
    const float* __restrict__ emb, const unsigned long long* __restrict__ sread,
    unsigned long long* __restrict__ sreset,
    const float* __restrict__ W_ih, const float* __restrict__ b_ih,
    const float* __restrict__ W_hh, const float* __restrict__ b_hh,
    float* __restrict__ hdst) {
    __shared__ __align__(16) float xs[64 * 65];     // [kk][b], stride 65 -> conflict-free
    __shared__ __align__(16) float hs[64 * 65];
    int tx = threadIdx.x, ty = threadIdx.y;
    int tid = ty * 64 + tx;
    int i = __builtin_amdgcn_readfirstlane((int)(blockIdx.x * 4 + ty)); // wave-uniform -> scalar W loads
    const float* wih_r = W_ih + (size_t)i * E;
    const float* wih_z = W_ih + (size_t)(H + i) * E;
    const float* wih_n = W_ih + (size_t)(2 * H + i) * E;
    const float* whh_r = W_hh + (size_t)i * H;
    const float* whh_z = W_hh + (size_t)(H + i) * H;
    const float* whh_n = W_hh + (size_t)(2 * H + i) * H;

    float air = 0.f, aiz = 0.f, ain = 0.f, ahr = 0.f, ahz = 0.f, ahn = 0.f;

    for (int k0 = 0; k0 < E; k0 += 64) {
        __syncthreads();
#pragma unroll
        for (int j = 0; j < 4; ++j) {
            int q = tid + j * 256;
            int row = q >> 4;                       // batch row 0..63
            int c4 = q & 15;                        // float4 col within 64-chunk
            const float* xrow;
            if (sread) {
                int id = (int)(~(unsigned)sread[row]);
                xrow = emb + (size_t)id * E;
            } else {
                xrow = x0 + (size_t)row * E;
            }
            float4 xv = *(const float4*)(xrow + k0 + c4 * 4);
            float4 hv = *(const float4*)(hsrc + (size_t)row * H + k0 + c4 * 4);
            int kk = c4 * 4;
            xs[(kk + 0) * 65 + row] = xv.x;
            xs[(kk + 1) * 65 + row] = xv.y;
            xs[(kk + 2) * 65 + row] = xv.z;
            xs[(kk + 3) * 65 + row] = xv.w;
            hs[(kk + 0) * 65 + row] = hv.x;
            hs[(kk + 1) * 65 + row] = hv.y;
            hs[(kk + 2) * 65 + row] = hv.z;
            hs[(kk + 3) * 65 + row] = hv.w;
        }
        __syncthreads();
#pragma unroll 4
        for (int kk = 0; kk < 64; ++kk) {
            float xv = xs[kk * 65 + tx];
            float hv = hs[kk * 65 + tx];
            int k = k0 + kk;
            air = fmaf(xv, wih_r[k], air);
            aiz = fmaf(xv, wih_z[k], aiz);
            ain = fmaf(xv, wih_n[k], ain);
            ahr = fmaf(hv, whh_r[k], ahr);
            ahz = fmaf(hv, whh_z[k], ahz);
            ahn = fmaf(hv, whh_n[k], ahn);
        }
    }
    float ir = air + b_ih[i];
    float iz = aiz + b_ih[H + i];
    float inn = ain + b_ih[2 * H + i];
    float hr = ahr + b_hh[i];
    float hz = ahz + b_hh[H + i];
    float hn = ahn + b_hh[2 * H + i];
    float r  = 1.0f / (1.0f + expf(-(ir + hr)));
    float zg = 1.0f / (1.0f + expf(-(iz + hz)));
    float nn = tanhf(inn + r * hn);
    float hp = hsrc[(size_t)tx * H + i];
    hdst[(size_t)tx * H + i] = (1.0f - zg) * nn + zg * hp;

    if (blockIdx.x == 0 && tid < 64) sreset[tid] = 0ull;  // reset this step's slots before logits
}

// ---------- kernel 3: logits = h_new @ W_fc.T + b_fc; write out; atomic argmax ----------
// grid 500 (n-tiles of 64), block 256. 64b x 64n tile, 4x4 per thread, K-chunk 64.
__global__ __launch_bounds__(256) void logits_kernel(
    const float* __restrict__ h, const float* __restrict__ W_fc,
    const float* __restrict__ b_fc, float* __restrict__ out,
    int t, unsigned long long* __restrict__ slots) {
    __shared__ __align__(16) float smem[2 * 64 * 68];   // hsT [kk][b] s=68, wsT [kk][n] s=68
    float* hsT = smem;
    float* wsT = smem + 64 * 68;
    int tid = threadIdx.x;
    int n0 = blockIdx.x * 64;
    int tx = tid & 15;      // n quad
    int ty = tid >> 4;      // b quad
    float acc[4][4] = {{0.f}};

    for (int k0 = 0; k0 < H; k0 += 64) {
        __syncthreads();
#pragma unroll
        for (int j = 0; j < 4; ++j) {
            int q = tid + j * 256;
            int row = q >> 4;
            int c4 = q & 15;
            float4 hv = *(const float4*)(h + (size_t)row * H + k0 + c4 * 4);
            float4 wv = *(const float4*)(W_fc + (size_t)(n0 + row) * H + k0 + c4 * 4);
            int kk = c4 * 4;
            hsT[(kk + 0) * 68 + row] = hv.x;
            hsT[(kk + 1) * 68 + row] = hv.y;
            hsT[(kk + 2) * 68 + row] = hv.z;
            hsT[(kk + 3) * 68 + row] = hv.w;
            wsT[(kk + 0) * 68 + row] = wv.x;
            wsT[(kk + 1) * 68 + row] = wv.y;
            wsT[(kk + 2) * 68 + row] = wv.z;
            wsT[(kk + 3) * 68 + row] = wv.w;
        }
        __syncthreads();
#pragma unroll 8
        for (int kk = 0; kk < 64; ++kk) {
            float4 hv = *(const float4*)(hsT + kk * 68 + ty * 4);  // 16B aligned
            float4 wv = *(const float4*)(wsT + kk * 68 + tx * 4);
            acc[0][0] = fmaf(hv.x, wv.x, acc[0][0]);
            acc[0][1] = fmaf(hv.x, wv.y, acc[0][1]);
            acc[0][2] = fmaf(hv.x, wv.z, acc[0][2]);
            acc[0][3] = fmaf(hv.x, wv.w, acc[0][3]);
            acc[1][0] = fmaf(hv.y, wv.x, acc[1][0]);
            acc[1][1] = fmaf(hv.y, wv.y, acc[1][1]);
            acc[1][2] = fmaf(hv.y, wv.z, acc[1][2]);
            acc[1][3] = fmaf(hv.y, wv.w, acc[1][3]);
            acc[2][0] = fmaf(hv.z, wv.x, acc[2][0]);
            acc[2][1] = fmaf(hv.z, wv.y, acc[2][1]);
            acc[2][2] = fmaf(hv.z, wv.z, acc[2][2]);
            acc[2][3] = fmaf(hv.z, wv.w, acc[2][3]);
            acc[3][0] = fmaf(hv.w, wv.x, acc[3][0]);
            acc[3][1] = fmaf(hv.w, wv.y, acc[3][1]);
            acc[3][2] = fmaf(hv.w, wv.z, acc[3][2]);
            acc[3][3] = fmaf(hv.w, wv.w, acc[3][3]);
        }
    }

    int nbase = n0 + tx * 4;
    float4 bv = *(const float4*)(b_fc + nbase);
    unsigned long long mk[4];
#pragma unroll
    for (int i = 0; i < 4; ++i) {
        int b = ty * 4 + i;
        float r0 = acc[i][0] + bv.x;
        float r1 = acc[i][1] + bv.y;
        float r2 = acc[i][2] + bv.z;
        float r3 = acc[i][3] + bv.w;
        float4 res = make_float4(r0, r1, r2, r3);
        *(float4*)(out + ((size_t)b * T + t) * V + nbase) = res;
        unsigned long long m = pack_key(r0, nbase);
        unsigned long long m1 = pack_key(r1, nbase + 1);
        unsigned long long m2 = pack_key(r2, nbase + 2);
        unsigned long long m3 = pack_key(r3, nbase + 3);
        if (m1 > m) m = m1;
        if (m2 > m) m = m2;
        if (m3 > m) m = m3;
        mk[i] = m;
    }

    __syncthreads();                                  // compute reads done; alias smem
    unsigned long long* red = (unsigned long long*)smem;  // [64][16]
#pragma unroll
    for (int i = 0; i < 4; ++i) red[(ty * 4 + i) * 16 + tx] = mk[i];
    __syncthreads();
    if (tid < 64) {
        unsigned long long m = red[tid * 16];
#pragma unroll
        for (int j = 1; j < 16; ++j) {
            unsigned long long v = red[tid * 16 + j];
            if (v > m) m = v;
        }
        atomicMax(slots + tid, m);
    }
}

// ---------- host ----------
extern "C" void kernel_launch(void* const* d_in, const int* in_sizes, int n_in,
                              void* d_out, int out_size, void* d_ws, size_t ws_size,
                              hipStream_t stream) {
    const float* z      = (const float*)d_in[0];
    const float* emb    = (const float*)d_in[1];
    const float* W_proj = (const float*)d_in[2];
    const float* b_proj = (const float*)d_in[3];
    const float* W_ih   = (const float*)d_in[4];
    const float* b_ih   = (const float*)d_in[5];
    const float* W_hh   = (const float*)d_in[6];
    const float* b_hh   = (const float*)d_in[7];
    const float* W_fc   = (const float*)d_in[8];
    const float* b_fc   = (const float*)d_in[9];
    float* out = (float*)d_out;

    float* hbuf = (float*)d_ws;                                   // 2 * 64*512 floats
    unsigned long long* slots =
        (unsigned long long*)((char*)d_ws + 2 * B * H * sizeof(float)); // 2 * 64 slots

    init_kernel<<<128, 256, 0, stream>>>(z, W_proj, b_proj, hbuf, slots);

    for (int t = 0; t < T; ++t) {
        const float* hsrc = hbuf + (size_t)(t & 1) * (B * H);
        float* hdst = hbuf + (size_t)((t + 1) & 1) * (B * H);
        const unsigned long long* sread = (t == 0) ? nullptr : slots + ((t - 1) & 1) * B;
        unsigned long long* scur = slots + (t & 1) * B;

        gru_kernel<<<128, dim3(64, 4), 0, stream>>>(
            hsrc, hbuf, emb, sread, scur, W_ih, b_ih, W_hh, b_hh, hdst);
        logits_kernel<<<500, 256, 0, stream>>>(hdst, W_fc, b_fc, out, t, scur);
    }
}